// Round 7
// baseline (358.995 us; speedup 1.0000x reference)
//
#include <hip/hip_runtime.h>
#include <hip/hip_fp16.h>

#define BB 512
#define TT 2048

typedef _Float16 half2v __attribute__((ext_vector_type(2)));

// ---------- fast math helpers ----------
__device__ __forceinline__ float fexp2(float x){ return __builtin_amdgcn_exp2f(x); }
__device__ __forceinline__ float frcp(float x){ return __builtin_amdgcn_rcpf(x); }

#define QB(v, ctrl) __int_as_float(__builtin_amdgcn_mov_dpp(__float_as_int(v), (ctrl), 0xF, 0xF, true))
#define RL(v, l)    __builtin_amdgcn_readlane((v), (l))

// ---------- fused producer/consumer, round 7: I-cache shrink ----------
// Identical layout/math to round 6 (235us). Round-6 residual: +35 cy/step over the
// bare 240-cy chain; identified bank-conflict/barrier/ds_read costs only explain
// ~8-10. Hypothesis: the ~40KB unrolled loop body (FILL 16KB + CONSUME 23KB)
// exceeds the 32KB I$; the latency-bound consumer wave cannot hide fetch bubbles.
// Fix is footprint-only, math byte-identical:
//   * CONSUME: 4-iter inner loop (2-row register prefetch + 16 STEPs)  ~6.5KB
//   * FILL: dynamic 52-iter loop (producer has 5-9x slack)             ~0.5KB
//   * consumer wave s_setprio(1) (may share a SIMD with the other block's producer)
__global__ __launch_bounds__(128, 1) void k_pc2(
    const float* __restrict__ x,
    const float* __restrict__ Wih,
    const float* __restrict__ Whh,
    const float* __restrict__ bih,
    const float* __restrict__ bhh,
    const float* __restrict__ fcw,
    const float* __restrict__ fcb,
    float* __restrict__ out)
{
  __shared__ unsigned short xgb[2][8][424];   // [buf][tg][53 rows x 8 u]

  const int tid  = threadIdx.x;
  const int wid  = tid >> 6;
  const int lane = tid & 63;
  const int b    = blockIdx.x;

  // ---- producer state (persists across chunk loop)
  float xr[13];
  const int  tgl = lane >> 3, u = lane & 7;
  const float* xbase = x + ((size_t)b*TT + tgl*8 + u)*13;   // t = c*64 + tgl*8 + u
  unsigned short fc16 = 0;

  // ---- consumer state (persists across chunk loop; k_rec7 verbatim)
  float w[13];
  float gm = 1.f, ga = 0.f, fcbias = 0.f;
  int   e = 0;
  float h = 0.f, c_ = 0.f;            // c_ carries -2*log2e*c
  float hb0=0,hb1=0,hb2=0,hb3=0,hb4=0,hb5=0,hb6=0,hb7=0,hb8=0,hb9=0,hb10=0,hb11=0,hb12=0;
  float p0=0,p1=0,p2=0,p3=0,p4=0,p5=0,p6=0,p7=0;
  float* op = out + (size_t)b*TT;
  bool first = true;

// producer: load chunk c_'s 13 x values (coalesced per-lane dwords; issued one
// chunk ahead -- the full consumer chunk (~15K cy) covers HBM latency)
#define XLOAD(c_) do {                                                        \
    const float* p_ = xbase + (size_t)(c_)*64*13;                             \
    _Pragma("unroll")                                                         \
    for (int k=0;k<13;++k) xr[k] = p_[k];                                     \
  } while(0)

// producer: compute + write one chunk in the exact k_xg3 row format.
// Dynamic loop (unroll 1): ~0.5KB static; producer slack absorbs loop overhead.
#define FILL(bi_) do {                                                        \
    unsigned short* dst_ = &xgb[bi_][tgl][0];                                 \
    _Pragma("unroll 1")                                                       \
    for (int g=0; g<52; ++g){                                                 \
      float acc = bih[g] + bhh[g];                                            \
      _Pragma("unroll")                                                       \
      for (int k=0;k<13;++k) acc = fmaf(Wih[g*13+k], xr[k], acc);             \
      const float sc = (g>=26 && g<39) ? -2.8853900817779268f                 \
                                       : -1.4426950408889634f;                \
      dst_[g*8 + u] = __half_as_ushort(__float2half(acc*sc));                 \
    }                                                                         \
    dst_[52*8 + u] = fc16;                                                    \
  } while(0)

#define CAPTURE(gv_, u_) do {                                                 \
    if ((u_)==1) p0=(gv_); else if ((u_)==2) p1=(gv_);                        \
    else if ((u_)==3) p2=(gv_); else if ((u_)==4) p3=(gv_);                   \
    else if ((u_)==5) p4=(gv_); else if ((u_)==6) p5=(gv_);                   \
    else if ((u_)==7) p6=(gv_);                                               \
    else { p7=(gv_);                                                          \
      if (!first){                                                            \
        if (lane == 52){                                                      \
          float4* o4 = (float4*)op;                                           \
          o4[0] = make_float4(p0,p1,p2,p3);                                   \
          o4[1] = make_float4(p4,p5,p6,p7);                                   \
        }                                                                     \
        op += 8;                                                              \
      }                                                                       \
      first = false;                                                          \
    }                                                                         \
  } while(0)

#define STEP(xv_, u_) do {                                                    \
    float dA = fmaf(w[0], hb0, (xv_));                                        \
    dA = fmaf(w[1], hb1, dA);                                                 \
    dA = fmaf(w[2], hb2, dA);                                                 \
    dA = fmaf(w[3], hb3, dA);                                                 \
    dA = fmaf(w[4], hb4, dA);                                                 \
    float dB = w[5]*hb5;                                                      \
    dB = fmaf(w[6], hb6, dB);                                                 \
    dB = fmaf(w[7], hb7, dB);                                                 \
    dB = fmaf(w[8], hb8, dB);                                                 \
    float dC = w[9]*hb9;                                                      \
    dC = fmaf(w[10], hb10, dC);                                               \
    dC = fmaf(w[11], hb11, dC);                                               \
    dC = fmaf(w[12], hb12, dC);                                               \
    float s  = (dB + dC) + dA;                                                \
    float r  = frcp(1.f + fexp2(s));                                          \
    float g  = fmaf(gm, r, ga);                                               \
    CAPTURE(g, u_);                                                           \
    float ggb = QB(g, 0xAA);                                                  \
    float gfb = QB(g, 0x55);                                                  \
    float gob = QB(g, 0xFF);                                                  \
    float go2 = gob + gob;                                                    \
    c_ = fmaf(gfb, c_, g*ggb);                                                \
    float r2 = frcp(1.f + fexp2(c_));                                         \
    h = fmaf(go2, r2, -gob);                                                  \
    int hv_ = __float_as_int(h);                                              \
    hb0  = __int_as_float(RL(hv_, 0));                                        \
    hb1  = __int_as_float(RL(hv_, 4));                                        \
    hb2  = __int_as_float(RL(hv_, 8));                                        \
    hb3  = __int_as_float(RL(hv_, 12));                                       \
    hb4  = __int_as_float(RL(hv_, 16));                                       \
    hb5  = __int_as_float(RL(hv_, 20));                                       \
    hb6  = __int_as_float(RL(hv_, 24));                                       \
    hb7  = __int_as_float(RL(hv_, 28));                                       \
    hb8  = __int_as_float(RL(hv_, 32));                                       \
    hb9  = __int_as_float(RL(hv_, 36));                                       \
    hb10 = __int_as_float(RL(hv_, 40));                                       \
    hb11 = __int_as_float(RL(hv_, 44));                                       \
    hb12 = __int_as_float(RL(hv_, 48));                                       \
  } while(0)

#define XLO(w_) (float)(__builtin_bit_cast(half2v, (w_)).x)
#define XHI(w_) (float)(__builtin_bit_cast(half2v, (w_)).y)

#define STEP8(Q) do {                                                         \
    STEP(XLO(Q.x), 0); STEP(XHI(Q.x), 1);                                     \
    STEP(XLO(Q.y), 2); STEP(XHI(Q.y), 3);                                     \
    STEP(XLO(Q.z), 4); STEP(XHI(Q.z), 5);                                     \
    STEP(XLO(Q.w), 6); STEP(XHI(Q.w), 7);                                     \
  } while(0)

// consumer: one chunk = 8 tg rows; 4-iter inner loop, 2-row register prefetch.
// Static footprint ~6.5KB (vs 23KB fully unrolled in round 6).
#define CONSUME(bi_) do {                                                     \
    const char* base_ = (const char*)&xgb[bi_][0][0] + (size_t)e*16;          \
    uint4 ra_ = *(const uint4*)(base_ + 0*848);                               \
    uint4 rb_ = *(const uint4*)(base_ + 1*848);                               \
    _Pragma("unroll 1")                                                       \
    for (int rr=0; rr<4; ++rr){                                               \
      uint4 ca_ = ra_, cb_ = rb_;                                             \
      const int rn_ = (rr<3) ? (2*rr+2) : 0;     /* tail: dummy re-read */    \
      ra_ = *(const uint4*)(base_ + rn_*848);                                 \
      rb_ = *(const uint4*)(base_ + (rn_+1)*848);                             \
      STEP8(ca_); STEP8(cb_);                                                 \
    }                                                                         \
  } while(0)

  if (wid == 1){
    // -------- producer setup + chunk 0 --------
    fc16 = __half_as_ushort(__float2half(-1.4426950408889634f * fcb[0]));
    XLOAD(0);
    FILL(0);
    XLOAD(1);                 // prefetch chunk 1 (consumed next FILL)
  } else {
    // -------- consumer setup (k_rec7 verbatim) --------
    __builtin_amdgcn_s_setprio(1);        // favor the latency-critical chain wave
    const int q  = lane & 3;
    const int j  = lane >> 2;             // 0..15 (13..15 padding)
    const int jc = (j < 13) ? j : 12;
    e = (lane == 52) ? 52 : q*13 + jc;
    const float kq = (q==2) ? -2.8853900817779268f : -1.4426950408889634f;
    gm = (q==2) ? -5.7707801635558536f : 1.f;
    ga = (q==2) ?  2.8853900817779268f : 0.f;
    fcbias = -1.4426950408889634f * fcb[0];
    const float* wsrc = (lane == 52) ? fcw : (Whh + (size_t)e*13);
    #pragma unroll
    for (int k=0;k<13;k++) w[k] = wsrc[k]*kq;
  }
  __syncthreads();                                  // chunk 0 ready

  for (int c=0; c<31; ++c){
    if (wid == 1){
      FILL((c+1)&1);                                // chunk c+1 (uses prefetched xr)
      if (c < 30) XLOAD(c+2);                       // prefetch chunk c+2
    } else {
      CONSUME(c&1);                                 // chunk c
    }
    __syncthreads();                                // chunk c+1 ready
  }

  if (wid == 0){
    CONSUME(31&1);                                  // chunk 31

    // epilogue: out[2047] = sigmoid(fc_b + fc_w·h_2047); lane 52 stores p0..p6 + r
    float s = fcbias;
    s = fmaf(w[0],  hb0,  s);
    s = fmaf(w[1],  hb1,  s);
    s = fmaf(w[2],  hb2,  s);
    s = fmaf(w[3],  hb3,  s);
    s = fmaf(w[4],  hb4,  s);
    s = fmaf(w[5],  hb5,  s);
    s = fmaf(w[6],  hb6,  s);
    s = fmaf(w[7],  hb7,  s);
    s = fmaf(w[8],  hb8,  s);
    s = fmaf(w[9],  hb9,  s);
    s = fmaf(w[10], hb10, s);
    s = fmaf(w[11], hb11, s);
    s = fmaf(w[12], hb12, s);
    float r = frcp(1.f + fexp2(s));
    if (lane == 52){
      float4* o4 = (float4*)op;                     // op == out + b*TT + 2040 here
      o4[0] = make_float4(p0,p1,p2,p3);
      o4[1] = make_float4(p4,p5,p6,r);
    }
  }

#undef CONSUME
#undef STEP8
#undef STEP
#undef CAPTURE
#undef FILL
#undef XLOAD
#undef XLO
#undef XHI
}

extern "C" void kernel_launch(void* const* d_in, const int* in_sizes, int n_in,
                              void* d_out, int out_size, void* d_ws, size_t ws_size,
                              hipStream_t stream)
{
  const float* x   = (const float*)d_in[0];
  const float* Wih = (const float*)d_in[1];
  const float* Whh = (const float*)d_in[2];
  const float* bih = (const float*)d_in[3];
  const float* bhh = (const float*)d_in[4];
  const float* fcw = (const float*)d_in[5];
  const float* fcb = (const float*)d_in[6];
  float* out = (float*)d_out;

  (void)d_ws; (void)ws_size;   // fully fused: no workspace
  k_pc2<<<dim3(BB), dim3(128), 0, stream>>>(x, Wih, Whh, bih, bhh, fcw, fcb, out);
}

// Round 8
// 354.211 us; speedup vs baseline: 1.0135x; 1.0135x over previous
//
#include <hip/hip_runtime.h>
#include <hip/hip_fp16.h>

#define BB 512
#define TT 2048

typedef _Float16 half2v __attribute__((ext_vector_type(2)));

// ---------- fast math helpers ----------
__device__ __forceinline__ float fexp2(float x){ return __builtin_amdgcn_exp2f(x); }
__device__ __forceinline__ float frcp(float x){ return __builtin_amdgcn_rcpf(x); }

#define QB(v, ctrl) __int_as_float(__builtin_amdgcn_mov_dpp(__float_as_int(v), (ctrl), 0xF, 0xF, true))
#define RL(v, l)    __builtin_amdgcn_readlane((v), (l))

// ---------- fused producer/consumer, round 8 ----------
// = round 6 (best: 235us kernel) with PRODUCER BYTE-IDENTICAL, plus two
// consumer-only scheduling tweaks (one-variable discipline restored):
//   (1) row reads interleaved with STEP8 groups (still fully unrolled):
//       round 6 issued all 8 ds_read_b128 at chunk entry and stalled on the
//       batch lgkmcnt wait; two-ahead spreading keeps one read in front of
//       the chain -> removes the chunk-entry bubble.
//   (2) s_setprio(1) on the consumer wave: with 2 blocks/CU a consumer can
//       share a SIMD with the other block's producer; priority keeps the
//       latency-critical chain wave issuing first.
// Round-7 lesson: FILL must stay fully unrolled (rolled FILL re-exposes
// per-iteration s_load latency 52x/chunk = the round-2 producer failure).
__global__ __launch_bounds__(128, 1) void k_pc3(
    const float* __restrict__ x,
    const float* __restrict__ Wih,
    const float* __restrict__ Whh,
    const float* __restrict__ bih,
    const float* __restrict__ bhh,
    const float* __restrict__ fcw,
    const float* __restrict__ fcb,
    float* __restrict__ out)
{
  __shared__ unsigned short xgb[2][8][424];   // [buf][tg][53 rows x 8 u]

  const int tid  = threadIdx.x;
  const int wid  = tid >> 6;
  const int lane = tid & 63;
  const int b    = blockIdx.x;

  // ---- producer state (persists across chunk loop)
  float xr[13];
  const int  tgl = lane >> 3, u = lane & 7;
  const float* xbase = x + ((size_t)b*TT + tgl*8 + u)*13;   // t = c*64 + tgl*8 + u
  unsigned short fc16 = 0;

  // ---- consumer state (persists across chunk loop; k_rec7 verbatim)
  float w[13];
  float gm = 1.f, ga = 0.f, fcbias = 0.f;
  int   e = 0;
  float h = 0.f, c_ = 0.f;            // c_ carries -2*log2e*c
  float hb0=0,hb1=0,hb2=0,hb3=0,hb4=0,hb5=0,hb6=0,hb7=0,hb8=0,hb9=0,hb10=0,hb11=0,hb12=0;
  float p0=0,p1=0,p2=0,p3=0,p4=0,p5=0,p6=0,p7=0;
  float* op = out + (size_t)b*TT;
  bool first = true;

// producer: load chunk c_'s 13 x values (coalesced per-lane dwords; issued one
// chunk ahead -- the full consumer chunk (~15K cy) covers HBM latency)
#define XLOAD(c_) do {                                                        \
    const float* p_ = xbase + (size_t)(c_)*64*13;                             \
    _Pragma("unroll")                                                         \
    for (int k=0;k<13;++k) xr[k] = p_[k];                                     \
  } while(0)

// producer: compute + write one chunk in the exact k_xg3 row format.
// FULLY UNROLLED (round-6 form; round 7 proved rolling this regresses).
#define FILL(bi_) do {                                                        \
    unsigned short* dst_ = &xgb[bi_][tgl][0];                                 \
    _Pragma("unroll 4")                                                       \
    for (int g=0; g<52; ++g){                                                 \
      float acc = bih[g] + bhh[g];                                            \
      _Pragma("unroll")                                                       \
      for (int k=0;k<13;++k) acc = fmaf(Wih[g*13+k], xr[k], acc);             \
      const float sc = (g>=26 && g<39) ? -2.8853900817779268f                 \
                                       : -1.4426950408889634f;                \
      dst_[g*8 + u] = __half_as_ushort(__float2half(acc*sc));                 \
    }                                                                         \
    dst_[52*8 + u] = fc16;                                                    \
  } while(0)

#define CAPTURE(gv_, u_) do {                                                 \
    if ((u_)==1) p0=(gv_); else if ((u_)==2) p1=(gv_);                        \
    else if ((u_)==3) p2=(gv_); else if ((u_)==4) p3=(gv_);                   \
    else if ((u_)==5) p4=(gv_); else if ((u_)==6) p5=(gv_);                   \
    else if ((u_)==7) p6=(gv_);                                               \
    else { p7=(gv_);                                                          \
      if (!first){                                                            \
        if (lane == 52){                                                      \
          float4* o4 = (float4*)op;                                           \
          o4[0] = make_float4(p0,p1,p2,p3);                                   \
          o4[1] = make_float4(p4,p5,p6,p7);                                   \
        }                                                                     \
        op += 8;                                                              \
      }                                                                       \
      first = false;                                                          \
    }                                                                         \
  } while(0)

#define STEP(xv_, u_) do {                                                    \
    float dA = fmaf(w[0], hb0, (xv_));                                        \
    dA = fmaf(w[1], hb1, dA);                                                 \
    dA = fmaf(w[2], hb2, dA);                                                 \
    dA = fmaf(w[3], hb3, dA);                                                 \
    dA = fmaf(w[4], hb4, dA);                                                 \
    float dB = w[5]*hb5;                                                      \
    dB = fmaf(w[6], hb6, dB);                                                 \
    dB = fmaf(w[7], hb7, dB);                                                 \
    dB = fmaf(w[8], hb8, dB);                                                 \
    float dC = w[9]*hb9;                                                      \
    dC = fmaf(w[10], hb10, dC);                                               \
    dC = fmaf(w[11], hb11, dC);                                               \
    dC = fmaf(w[12], hb12, dC);                                               \
    float s  = (dB + dC) + dA;                                                \
    float r  = frcp(1.f + fexp2(s));                                          \
    float g  = fmaf(gm, r, ga);                                               \
    CAPTURE(g, u_);                                                           \
    float ggb = QB(g, 0xAA);                                                  \
    float gfb = QB(g, 0x55);                                                  \
    float gob = QB(g, 0xFF);                                                  \
    float go2 = gob + gob;                                                    \
    c_ = fmaf(gfb, c_, g*ggb);                                                \
    float r2 = frcp(1.f + fexp2(c_));                                         \
    h = fmaf(go2, r2, -gob);                                                  \
    int hv_ = __float_as_int(h);                                              \
    hb0  = __int_as_float(RL(hv_, 0));                                        \
    hb1  = __int_as_float(RL(hv_, 4));                                        \
    hb2  = __int_as_float(RL(hv_, 8));                                        \
    hb3  = __int_as_float(RL(hv_, 12));                                       \
    hb4  = __int_as_float(RL(hv_, 16));                                       \
    hb5  = __int_as_float(RL(hv_, 20));                                       \
    hb6  = __int_as_float(RL(hv_, 24));                                       \
    hb7  = __int_as_float(RL(hv_, 28));                                       \
    hb8  = __int_as_float(RL(hv_, 32));                                       \
    hb9  = __int_as_float(RL(hv_, 36));                                       \
    hb10 = __int_as_float(RL(hv_, 40));                                       \
    hb11 = __int_as_float(RL(hv_, 44));                                       \
    hb12 = __int_as_float(RL(hv_, 48));                                       \
  } while(0)

#define XLO(w_) (float)(__builtin_bit_cast(half2v, (w_)).x)
#define XHI(w_) (float)(__builtin_bit_cast(half2v, (w_)).y)

#define STEP8(Q) do {                                                         \
    STEP(XLO(Q.x), 0); STEP(XHI(Q.x), 1);                                     \
    STEP(XLO(Q.y), 2); STEP(XHI(Q.y), 3);                                     \
    STEP(XLO(Q.z), 4); STEP(XHI(Q.z), 5);                                     \
    STEP(XLO(Q.w), 6); STEP(XHI(Q.w), 7);                                     \
  } while(0)

// consumer: one chunk = 8 tg rows, fully unrolled, reads interleaved two-ahead
// so at most one outstanding ds_read sits in front of the chain.
#define CONSUME(bi_) do {                                                     \
    const char* base_ = (const char*)&xgb[bi_][0][0] + (size_t)e*16;          \
    uint4 r0 = *(const uint4*)(base_ + 0*848);                                \
    uint4 r1 = *(const uint4*)(base_ + 1*848);                                \
    STEP8(r0);                                                                \
    uint4 r2 = *(const uint4*)(base_ + 2*848);                                \
    STEP8(r1);                                                                \
    uint4 r3 = *(const uint4*)(base_ + 3*848);                                \
    STEP8(r2);                                                                \
    uint4 r4 = *(const uint4*)(base_ + 4*848);                                \
    STEP8(r3);                                                                \
    uint4 r5 = *(const uint4*)(base_ + 5*848);                                \
    STEP8(r4);                                                                \
    uint4 r6 = *(const uint4*)(base_ + 6*848);                                \
    STEP8(r5);                                                                \
    uint4 r7 = *(const uint4*)(base_ + 7*848);                                \
    STEP8(r6);                                                                \
    STEP8(r7);                                                                \
  } while(0)

  if (wid == 1){
    // -------- producer setup + chunk 0 (round 6 verbatim) --------
    fc16 = __half_as_ushort(__float2half(-1.4426950408889634f * fcb[0]));
    XLOAD(0);
    FILL(0);
    XLOAD(1);                 // prefetch chunk 1 (consumed next FILL)
  } else {
    // -------- consumer setup (k_rec7 verbatim) --------
    __builtin_amdgcn_s_setprio(1);        // favor the latency-critical chain wave
    const int q  = lane & 3;
    const int j  = lane >> 2;             // 0..15 (13..15 padding)
    const int jc = (j < 13) ? j : 12;
    e = (lane == 52) ? 52 : q*13 + jc;
    const float kq = (q==2) ? -2.8853900817779268f : -1.4426950408889634f;
    gm = (q==2) ? -5.7707801635558536f : 1.f;
    ga = (q==2) ?  2.8853900817779268f : 0.f;
    fcbias = -1.4426950408889634f * fcb[0];
    const float* wsrc = (lane == 52) ? fcw : (Whh + (size_t)e*13);
    #pragma unroll
    for (int k=0;k<13;k++) w[k] = wsrc[k]*kq;
  }
  __syncthreads();                                  // chunk 0 ready

  for (int c=0; c<31; ++c){
    if (wid == 1){
      FILL((c+1)&1);                                // chunk c+1 (uses prefetched xr)
      if (c < 30) XLOAD(c+2);                       // prefetch chunk c+2
    } else {
      CONSUME(c&1);                                 // chunk c
    }
    __syncthreads();                                // chunk c+1 ready
  }

  if (wid == 0){
    CONSUME(31&1);                                  // chunk 31

    // epilogue: out[2047] = sigmoid(fc_b + fc_w·h_2047); lane 52 stores p0..p6 + r
    float s = fcbias;
    s = fmaf(w[0],  hb0,  s);
    s = fmaf(w[1],  hb1,  s);
    s = fmaf(w[2],  hb2,  s);
    s = fmaf(w[3],  hb3,  s);
    s = fmaf(w[4],  hb4,  s);
    s = fmaf(w[5],  hb5,  s);
    s = fmaf(w[6],  hb6,  s);
    s = fmaf(w[7],  hb7,  s);
    s = fmaf(w[8],  hb8,  s);
    s = fmaf(w[9],  hb9,  s);
    s = fmaf(w[10], hb10, s);
    s = fmaf(w[11], hb11, s);
    s = fmaf(w[12], hb12, s);
    float r = frcp(1.f + fexp2(s));
    if (lane == 52){
      float4* o4 = (float4*)op;                     // op == out + b*TT + 2040 here
      o4[0] = make_float4(p0,p1,p2,p3);
      o4[1] = make_float4(p4,p5,p6,r);
    }
  }

#undef CONSUME
#undef STEP8
#undef STEP
#undef CAPTURE
#undef FILL
#undef XLOAD
#undef XLO
#undef XHI
}

extern "C" void kernel_launch(void* const* d_in, const int* in_sizes, int n_in,
                              void* d_out, int out_size, void* d_ws, size_t ws_size,
                              hipStream_t stream)
{
  const float* x   = (const float*)d_in[0];
  const float* Wih = (const float*)d_in[1];
  const float* Whh = (const float*)d_in[2];
  const float* bih = (const float*)d_in[3];
  const float* bhh = (const float*)d_in[4];
  const float* fcw = (const float*)d_in[5];
  const float* fcb = (const float*)d_in[6];
  float* out = (float*)d_out;

  (void)d_ws; (void)ws_size;   // fully fused: no workspace
  k_pc3<<<dim3(BB), dim3(128), 0, stream>>>(x, Wih, Whh, bih, bhh, fcw, fcb, out);
}

// Round 9
// 309.305 us; speedup vs baseline: 1.1607x; 1.1452x over previous
//
#include <hip/hip_runtime.h>
#include <hip/hip_fp16.h>

#define BB 512
#define TT 2048

typedef _Float16 half2v __attribute__((ext_vector_type(2)));

// ---------- fast math helpers ----------
__device__ __forceinline__ float fexp2(float x){ return __builtin_amdgcn_exp2f(x); }
__device__ __forceinline__ float frcp(float x){ return __builtin_amdgcn_rcpf(x); }

#define QB(v, ctrl) __int_as_float(__builtin_amdgcn_mov_dpp(__float_as_int(v), (ctrl), 0xF, 0xF, true))
#define RL(v, l)    __builtin_amdgcn_readlane((v), (l))

// ---------- fused producer/consumer, round 9 ----------
// = round 6 (best: 235us) with ONE change: producer XLOAD is issued BEFORE FILL
// into a second register set (xrA/xrB double-buffer), so the HBM loads land
// during FILL's ~4K cy of FMA work. Round 6 issued XLOAD immediately before
// __syncthreads, whose mandatory s_waitcnt vmcnt(0) drain exposed a full HBM
// latency (~1.5-1.9K cy/chunk = the bulk of the +35 cy/step residual vs the
// bare 240-cy chain). Consumer is byte-identical to round 6. NO setprio
// (rounds 7/8 A/B: setprio on this structure costs ~50us).
__global__ __launch_bounds__(128, 1) void k_pc4(
    const float* __restrict__ x,
    const float* __restrict__ Wih,
    const float* __restrict__ Whh,
    const float* __restrict__ bih,
    const float* __restrict__ bhh,
    const float* __restrict__ fcw,
    const float* __restrict__ fcb,
    float* __restrict__ out)
{
  __shared__ unsigned short xgb[2][8][424];   // [buf][tg][53 rows x 8 u]

  const int tid  = threadIdx.x;
  const int wid  = tid >> 6;
  const int lane = tid & 63;
  const int b    = blockIdx.x;

  // ---- producer state (persists across chunk loop)
  float xrA[13], xrB[13];
  const int  tgl = lane >> 3, u = lane & 7;
  const float* xbase = x + ((size_t)b*TT + tgl*8 + u)*13;   // t = c*64 + tgl*8 + u
  unsigned short fc16 = 0;

  // ---- consumer state (persists across chunk loop; k_rec7 verbatim)
  float w[13];
  float gm = 1.f, ga = 0.f, fcbias = 0.f;
  int   e = 0;
  float h = 0.f, c_ = 0.f;            // c_ carries -2*log2e*c
  float hb0=0,hb1=0,hb2=0,hb3=0,hb4=0,hb5=0,hb6=0,hb7=0,hb8=0,hb9=0,hb10=0,hb11=0,hb12=0;
  float p0=0,p1=0,p2=0,p3=0,p4=0,p5=0,p6=0,p7=0;
  float* op = out + (size_t)b*TT;
  bool first = true;

// producer: issue chunk c_'s 13 coalesced per-lane dwords into register set XR.
// Issued BEFORE FILL so the ~4K cy of FMA covers HBM latency; by the time the
// rotation (or the barrier's vmcnt(0) drain) needs them, they have landed.
#define XLOADB(c_, XR) do {                                                   \
    const float* p_ = xbase + (size_t)(c_)*64*13;                             \
    _Pragma("unroll")                                                         \
    for (int k=0;k<13;++k) XR[k] = p_[k];                                     \
  } while(0)

// rotate register double-buffer: A <- B (13 movs; vmcnt wait lands here, free)
#define PROT() do {                                                           \
    _Pragma("unroll")                                                         \
    for (int k=0;k<13;++k) xrA[k] = xrB[k];                                   \
  } while(0)

// producer: compute + write one chunk (from xrA) in the exact k_xg3 row format.
// unroll 4 (round-6 form; round 7 proved unroll 1 regresses via s_load latency).
#define FILL(bi_) do {                                                        \
    unsigned short* dst_ = &xgb[bi_][tgl][0];                                 \
    _Pragma("unroll 4")                                                       \
    for (int g=0; g<52; ++g){                                                 \
      float acc = bih[g] + bhh[g];                                            \
      _Pragma("unroll")                                                       \
      for (int k=0;k<13;++k) acc = fmaf(Wih[g*13+k], xrA[k], acc);            \
      const float sc = (g>=26 && g<39) ? -2.8853900817779268f                 \
                                       : -1.4426950408889634f;                \
      dst_[g*8 + u] = __half_as_ushort(__float2half(acc*sc));                 \
    }                                                                         \
    dst_[52*8 + u] = fc16;                                                    \
  } while(0)

#define CAPTURE(gv_, u_) do {                                                 \
    if ((u_)==1) p0=(gv_); else if ((u_)==2) p1=(gv_);                        \
    else if ((u_)==3) p2=(gv_); else if ((u_)==4) p3=(gv_);                   \
    else if ((u_)==5) p4=(gv_); else if ((u_)==6) p5=(gv_);                   \
    else if ((u_)==7) p6=(gv_);                                               \
    else { p7=(gv_);                                                          \
      if (!first){                                                            \
        if (lane == 52){                                                      \
          float4* o4 = (float4*)op;                                           \
          o4[0] = make_float4(p0,p1,p2,p3);                                   \
          o4[1] = make_float4(p4,p5,p6,p7);                                   \
        }                                                                     \
        op += 8;                                                              \
      }                                                                       \
      first = false;                                                          \
    }                                                                         \
  } while(0)

#define STEP(xv_, u_) do {                                                    \
    float dA = fmaf(w[0], hb0, (xv_));                                        \
    dA = fmaf(w[1], hb1, dA);                                                 \
    dA = fmaf(w[2], hb2, dA);                                                 \
    dA = fmaf(w[3], hb3, dA);                                                 \
    dA = fmaf(w[4], hb4, dA);                                                 \
    float dB = w[5]*hb5;                                                      \
    dB = fmaf(w[6], hb6, dB);                                                 \
    dB = fmaf(w[7], hb7, dB);                                                 \
    dB = fmaf(w[8], hb8, dB);                                                 \
    float dC = w[9]*hb9;                                                      \
    dC = fmaf(w[10], hb10, dC);                                               \
    dC = fmaf(w[11], hb11, dC);                                               \
    dC = fmaf(w[12], hb12, dC);                                               \
    float s  = (dB + dC) + dA;                                                \
    float r  = frcp(1.f + fexp2(s));                                          \
    float g  = fmaf(gm, r, ga);                                               \
    CAPTURE(g, u_);                                                           \
    float ggb = QB(g, 0xAA);                                                  \
    float gfb = QB(g, 0x55);                                                  \
    float gob = QB(g, 0xFF);                                                  \
    float go2 = gob + gob;                                                    \
    c_ = fmaf(gfb, c_, g*ggb);                                                \
    float r2 = frcp(1.f + fexp2(c_));                                         \
    h = fmaf(go2, r2, -gob);                                                  \
    int hv_ = __float_as_int(h);                                              \
    hb0  = __int_as_float(RL(hv_, 0));                                        \
    hb1  = __int_as_float(RL(hv_, 4));                                        \
    hb2  = __int_as_float(RL(hv_, 8));                                        \
    hb3  = __int_as_float(RL(hv_, 12));                                       \
    hb4  = __int_as_float(RL(hv_, 16));                                       \
    hb5  = __int_as_float(RL(hv_, 20));                                       \
    hb6  = __int_as_float(RL(hv_, 24));                                       \
    hb7  = __int_as_float(RL(hv_, 28));                                       \
    hb8  = __int_as_float(RL(hv_, 32));                                       \
    hb9  = __int_as_float(RL(hv_, 36));                                       \
    hb10 = __int_as_float(RL(hv_, 40));                                       \
    hb11 = __int_as_float(RL(hv_, 44));                                       \
    hb12 = __int_as_float(RL(hv_, 48));                                       \
  } while(0)

#define XLO(w_) (float)(__builtin_bit_cast(half2v, (w_)).x)
#define XHI(w_) (float)(__builtin_bit_cast(half2v, (w_)).y)

#define STEP8(Q) do {                                                         \
    STEP(XLO(Q.x), 0); STEP(XHI(Q.x), 1);                                     \
    STEP(XLO(Q.y), 2); STEP(XHI(Q.y), 3);                                     \
    STEP(XLO(Q.z), 4); STEP(XHI(Q.z), 5);                                     \
    STEP(XLO(Q.w), 6); STEP(XHI(Q.w), 7);                                     \
  } while(0)

// consumer: one chunk = 8 tg rows, round-6 batch-read form (best measured)
#define CONSUME(bi_) do {                                                     \
    const char* base_ = (const char*)&xgb[bi_][0][0] + (size_t)e*16;          \
    uint4 r0 = *(const uint4*)(base_ + 0*848);                                \
    uint4 r1 = *(const uint4*)(base_ + 1*848);                                \
    uint4 r2 = *(const uint4*)(base_ + 2*848);                                \
    uint4 r3 = *(const uint4*)(base_ + 3*848);                                \
    uint4 r4 = *(const uint4*)(base_ + 4*848);                                \
    uint4 r5 = *(const uint4*)(base_ + 5*848);                                \
    uint4 r6 = *(const uint4*)(base_ + 6*848);                                \
    uint4 r7 = *(const uint4*)(base_ + 7*848);                                \
    STEP8(r0); STEP8(r1); STEP8(r2); STEP8(r3);                               \
    STEP8(r4); STEP8(r5); STEP8(r6); STEP8(r7);                               \
  } while(0)

  if (wid == 1){
    // -------- producer setup + chunk 0 --------
    fc16 = __half_as_ushort(__float2half(-1.4426950408889634f * fcb[0]));
    XLOADB(0, xrA);           // chunk 0 raw x
    XLOADB(1, xrB);           // chunk 1 in flight during FILL(0)
    FILL(0);                  // sx chunk 0 (from xrA)
    PROT();                   // xrA <- xrB (chunk 1; loads landed during FILL)
  } else {
    // -------- consumer setup (k_rec7 verbatim; NO setprio) --------
    const int q  = lane & 3;
    const int j  = lane >> 2;             // 0..15 (13..15 padding)
    const int jc = (j < 13) ? j : 12;
    e = (lane == 52) ? 52 : q*13 + jc;
    const float kq = (q==2) ? -2.8853900817779268f : -1.4426950408889634f;
    gm = (q==2) ? -5.7707801635558536f : 1.f;
    ga = (q==2) ?  2.8853900817779268f : 0.f;
    fcbias = -1.4426950408889634f * fcb[0];
    const float* wsrc = (lane == 52) ? fcw : (Whh + (size_t)e*13);
    #pragma unroll
    for (int k=0;k<13;k++) w[k] = wsrc[k]*kq;
  }
  __syncthreads();                                  // chunk 0 ready

  for (int c=0; c<31; ++c){
    if (wid == 1){
      if (c < 30) XLOADB(c+2, xrB);                 // issue EARLY: lands during FILL
      FILL((c+1)&1);                                // chunk c+1 (from xrA)
      PROT();                                       // xrA <- xrB (wait absorbed here)
    } else {
      CONSUME(c&1);                                 // chunk c
    }
    __syncthreads();                                // chunk c+1 ready; vmcnt already 0
  }

  if (wid == 0){
    CONSUME(31&1);                                  // chunk 31

    // epilogue: out[2047] = sigmoid(fc_b + fc_w·h_2047); lane 52 stores p0..p6 + r
    float s = fcbias;
    s = fmaf(w[0],  hb0,  s);
    s = fmaf(w[1],  hb1,  s);
    s = fmaf(w[2],  hb2,  s);
    s = fmaf(w[3],  hb3,  s);
    s = fmaf(w[4],  hb4,  s);
    s = fmaf(w[5],  hb5,  s);
    s = fmaf(w[6],  hb6,  s);
    s = fmaf(w[7],  hb7,  s);
    s = fmaf(w[8],  hb8,  s);
    s = fmaf(w[9],  hb9,  s);
    s = fmaf(w[10], hb10, s);
    s = fmaf(w[11], hb11, s);
    s = fmaf(w[12], hb12, s);
    float r = frcp(1.f + fexp2(s));
    if (lane == 52){
      float4* o4 = (float4*)op;                     // op == out + b*TT + 2040 here
      o4[0] = make_float4(p0,p1,p2,p3);
      o4[1] = make_float4(p4,p5,p6,r);
    }
  }

#undef CONSUME
#undef STEP8
#undef STEP
#undef CAPTURE
#undef FILL
#undef PROT
#undef XLOADB
#undef XLO
#undef XHI
}

extern "C" void kernel_launch(void* const* d_in, const int* in_sizes, int n_in,
                              void* d_out, int out_size, void* d_ws, size_t ws_size,
                              hipStream_t stream)
{
  const float* x   = (const float*)d_in[0];
  const float* Wih = (const float*)d_in[1];
  const float* Whh = (const float*)d_in[2];
  const float* bih = (const float*)d_in[3];
  const float* bhh = (const float*)d_in[4];
  const float* fcw = (const float*)d_in[5];
  const float* fcb = (const float*)d_in[6];
  float* out = (float*)d_out;

  (void)d_ws; (void)ws_size;   // fully fused: no workspace
  k_pc4<<<dim3(BB), dim3(128), 0, stream>>>(x, Wih, Whh, bih, bhh, fcw, fcb, out);
}